// Round 22
// baseline (810.292 us; speedup 1.0000x reference)
//
#include <hip/hip_runtime.h>
#include <hip/hip_bf16.h>

typedef __attribute__((ext_vector_type(8))) __bf16 bf16x8;
typedef __attribute__((ext_vector_type(4))) float f32x4;
typedef __hip_bfloat16 bf16;

#define SCALE_Q 0.17677669529663687f

// exact-grade GELU: Abramowitz-Stegun 7.1.26 erf (|err| < 1.5e-7)
__device__ inline float gelu_f(float x) {
  const float ax = fabsf(x) * 0.70710678118654752f;
  const float t = __builtin_amdgcn_rcpf(__builtin_fmaf(0.3275911f, ax, 1.0f));
  const float poly = t * __builtin_fmaf(t, __builtin_fmaf(t, __builtin_fmaf(t,
                     __builtin_fmaf(t, 1.061405429f, -1.453152027f),
                     1.421413741f), -0.284496736f), 0.254829592f);
  const float er = __builtin_fmaf(-poly, __expf(-ax * ax), 1.0f);
  return 0.5f * x * (1.0f + copysignf(er, x));
}

// ---- weight fp32 -> bf16 in MFMA B-fragment order ----
template<int K, int KC>
__global__ void cvt_frag_kernel(const float* __restrict__ in, bf16* __restrict__ out, int total) {
  int i = blockIdx.x * 256 + threadIdx.x;
  if (i < total) {
    const int n = i / K, k = i - n * K;
    out[((n >> 4) * KC + (k >> 5)) * 512 + ((k >> 3) & 3) * 128 + (n & 15) * 8 + (k & 7)] =
        __float2bfloat16(in[i]);
  }
}

// ===== window mega-kernel v2: compact LDS (79KB -> 2 blocks/CU) =====
// Layout: [0,49152) per-head {Q 4KB swz | K 4KB swz} -> P [64][8][16] overlays after B3.
// [49152,73728) Ab (LN tile, phases 1-2) -> V (6x4KB swz, after B2a) -> O tile (after B4b).
// [73728,79128) rpl. All swizzles are the session-proven XOR pattern; math unchanged.
__global__ __launch_bounds__(512, 4) void win_attn(const float* __restrict__ x,
                                                   const float* __restrict__ n1w,
                                                   const float* __restrict__ n1b,
                                                   const bf16* __restrict__ qwt,
                                                   const float* __restrict__ qb,
                                                   const float* __restrict__ rpb,
                                                   const bf16* __restrict__ pwt,
                                                   const float* __restrict__ pb,
                                                   float* __restrict__ hbuf) {
  __shared__ __align__(16) char smem[79136];
  char* QK = smem;                        // head h: Q at h*8192, K at h*8192+4096
  char* VA = smem + 49152;                // Ab (3x8192) -> V (6x4096) -> O tile
  float* rpl = (float*)(smem + 73728);    // 6 x 225 floats

  const int tid = threadIdx.x;
  const int blk = blockIdx.x;             // window index b_
  const long m0 = (long)blk * 64;
  const int lane = tid & 63, wid = tid >> 6;
  const int lg = lane >> 4, lr = lane & 15;

  for (int t = tid; t < 1350; t += 512) {
    const int hh = t / 225, tt = t - hh * 225;
    rpl[hh * 225 + tt] = rpb[tt * 6 + hh];
  }

  // ---- Phase 1: LN1 + shifted-window gather -> Ab (VA region) ----
  #pragma unroll
  for (int t8 = 0; t8 < 8; t8++) {
    const int row = wid * 8 + t8;
    const long t = m0 + row;
    const int b_ = (int)(t >> 6), n = (int)(t & 63);
    const int b = b_ >> 10, wk = b_ & 1023, wi = wk >> 5, wj = wk & 31;
    const int hf = (wi * 8 + (n >> 3) + 4) & 255, wf = (wj * 8 + (n & 7) + 4) & 255;
    const long g = (((long)b * 256 + hf) * 256 + wf) * 192;
    const float x0 = x[g + lane], x1 = x[g + 64 + lane], x2 = x[g + 128 + lane];
    float s = x0 + x1 + x2;
    float s2 = x0 * x0 + x1 * x1 + x2 * x2;
    #pragma unroll
    for (int msk = 1; msk < 64; msk <<= 1) { s += __shfl_xor(s, msk); s2 += __shfl_xor(s2, msk); }
    const float mu = s * (1.0f / 192.0f);
    const float rstd = rsqrtf(s2 * (1.0f / 192.0f) - mu * mu + 1e-5f);
    #pragma unroll
    for (int p = 0; p < 3; p++) {
      const int ch = p * 64 + lane;
      const float xv = (p == 0) ? x0 : (p == 1) ? x1 : x2;
      const float v = (xv - mu) * rstd * n1w[ch] + n1b[ch];
      const int c = (ch >> 3) & 7;
      const int slot = c ^ (row & 7);
      *(unsigned short*)(VA + p * 8192 + row * 128 + slot * 16 + (ch & 7) * 2) =
          __builtin_bit_cast(unsigned short, __float2bfloat16(v));
    }
  }
  __syncthreads();  // B1: Ab + rpl ready

  // ---- Phase 2: QKV GEMM (reads Ab), then B2a, then epilogue -> Q/K (QK) + V (over Ab) ----
  {
    const int wrr = (wid >> 2) * 32;
    const int wcg = wid & 3;
    f32x4 acc[2][9];
    #pragma unroll
    for (int i = 0; i < 2; i++)
      #pragma unroll
      for (int j = 0; j < 9; j++) acc[i][j] = (f32x4){0.f, 0.f, 0.f, 0.f};
    const int c16base = wcg * 9;
    #pragma unroll
    for (int kc = 0; kc < 6; kc++) {
      const int q = kc >> 1;
      const int kk = (kc & 1) * 4 + lg;
      bf16x8 af[2], bfr[9];
      #pragma unroll
      for (int i = 0; i < 2; i++) {
        const int row = wrr + i * 16 + lr;
        af[i] = *(const bf16x8*)(VA + q * 8192 + row * 128 + ((kk ^ (row & 7)) * 16));
      }
      #pragma unroll
      for (int j = 0; j < 9; j++)
        bfr[j] = *(const bf16x8*)(qwt + ((c16base + j) * 6 + kc) * 512 + lane * 8);
      #pragma unroll
      for (int i = 0; i < 2; i++)
        #pragma unroll
        for (int j = 0; j < 9; j++)
          acc[i][j] = __builtin_amdgcn_mfma_f32_16x16x32_bf16(af[i], bfr[j], acc[i][j], 0, 0, 0);
    }
    __syncthreads();  // B2a: all Ab reads done -> V may overwrite Ab
    #pragma unroll
    for (int i = 0; i < 2; i++) {
      #pragma unroll
      for (int j = 0; j < 9; j++) {
        #pragma unroll
        for (int r = 0; r < 4; r++) {
          const int n = wrr + i * 16 + lg * 4 + r;
          const int cn = wcg * 144 + j * 16 + lr;
          float v = acc[i][j][r] + qb[cn];
          const int which = cn / 192, rem = cn - which * 192, head = rem >> 5, d = rem & 31;
          unsigned short us;
          if (which == 0) {
            v *= SCALE_Q; us = __builtin_bit_cast(unsigned short, __float2bfloat16(v));
            const int c = d >> 3, slot = c ^ (n & 3);
            *(unsigned short*)(QK + head * 8192 + n * 64 + slot * 16 + (d & 7) * 2) = us;
          } else if (which == 1) {
            us = __builtin_bit_cast(unsigned short, __float2bfloat16(v));
            const int c = d >> 3, slot = c ^ (n & 3);
            *(unsigned short*)(QK + head * 8192 + 4096 + n * 64 + slot * 16 + (d & 7) * 2) = us;
          } else {
            us = __builtin_bit_cast(unsigned short, __float2bfloat16(v));
            const int c = n >> 3, slot = c ^ (d & 7);
            *(unsigned short*)(VA + head * 4096 + d * 128 + slot * 16 + (n & 7) * 2) = us;
          }
        }
      }
    }
  }
  __syncthreads();  // B2: Q/K/V ready

  // ---- Phase 3: attention (head = wid for wid<6) ----
  const f32x4 z4 = {0.f, 0.f, 0.f, 0.f};
  f32x4 s[4][4];
  const int head = wid;
  if (wid < 6) {
    bf16x8 a[4], b[4];
    #pragma unroll
    for (int fi = 0; fi < 4; fi++) {
      const int row = fi * 16 + lr;
      a[fi] = *(const bf16x8*)(QK + head * 8192 + row * 64 + ((lg ^ (row & 3)) * 16));
    }
    #pragma unroll
    for (int fj = 0; fj < 4; fj++) {
      const int row = fj * 16 + lr;
      b[fj] = *(const bf16x8*)(QK + head * 8192 + 4096 + row * 64 + ((lg ^ (row & 3)) * 16));
    }
    #pragma unroll
    for (int fi = 0; fi < 4; fi++)
      #pragma unroll
      for (int fj = 0; fj < 4; fj++)
        s[fi][fj] = __builtin_amdgcn_mfma_f32_16x16x32_bf16(a[fi], b[fj], z4, 0, 0, 0);
  }
  __syncthreads();  // B3: all Q/K reads done -> P may overlay

  char* P = QK + head * 8192;   // P [64 rows][8 slots][16B] overlays Q+K of this head
  if (wid < 6) {
    const int wk = blk & 1023; const int wi = wk >> 5, wj = wk & 31;
    const bool eh = (wi == 31), ew = (wj == 31);
    const float* rps = rpl + head * 225;
    #pragma unroll
    for (int fi = 0; fi < 4; fi++) {
      #pragma unroll
      for (int r = 0; r < 4; r++) {
        const int n = fi * 16 + lg * 4 + r;
        const int i1 = n >> 3, j1 = n & 7;
        const int labn = (eh ? (i1 < 4 ? 3 : 6) : 0) + (ew ? (j1 < 4 ? 1 : 2) : 0);
        float vals[4];
        #pragma unroll
        for (int fj = 0; fj < 4; fj++) {
          const int m = fj * 16 + lr;
          const int i2 = m >> 3, j2 = m & 7;
          const int labm = (eh ? (i2 < 4 ? 3 : 6) : 0) + (ew ? (j2 < 4 ? 1 : 2) : 0);
          vals[fj] = s[fi][fj][r] + rps[(i1 - i2 + 7) * 15 + (j1 - j2 + 7)]
                   + (labn != labm ? -100.0f : 0.0f);
        }
        float mx = fmaxf(fmaxf(vals[0], vals[1]), fmaxf(vals[2], vals[3]));
        #pragma unroll
        for (int msk = 1; msk < 16; msk <<= 1) mx = fmaxf(mx, __shfl_xor(mx, msk));
        float pe[4]; float sum = 0.f;
        #pragma unroll
        for (int fj = 0; fj < 4; fj++) { pe[fj] = __expf(vals[fj] - mx); sum += pe[fj]; }
        #pragma unroll
        for (int msk = 1; msk < 16; msk <<= 1) sum += __shfl_xor(sum, msk);
        const float rinv = 1.0f / sum;
        #pragma unroll
        for (int fj = 0; fj < 4; fj++) {
          const int m = fj * 16 + lr;
          const int c = m >> 3, slot = c ^ (n & 7);
          *(unsigned short*)(P + n * 128 + slot * 16 + (m & 7) * 2) =
              __builtin_bit_cast(unsigned short, __float2bfloat16(pe[fj] * rinv));
        }
      }
    }
  }
  __syncthreads();  // B4: P ready

  f32x4 o[4][2];
  if (wid < 6) {
    #pragma unroll
    for (int fi = 0; fi < 4; fi++)
      #pragma unroll
      for (int fd = 0; fd < 2; fd++) o[fi][fd] = z4;
    #pragma unroll
    for (int ks = 0; ks < 2; ks++) {
      const int c2 = ks * 4 + lg;
      bf16x8 pa[4], vb[2];
      #pragma unroll
      for (int fi = 0; fi < 4; fi++) {
        const int row = fi * 16 + lr;
        pa[fi] = *(const bf16x8*)(P + row * 128 + ((c2 ^ (row & 7)) * 16));
      }
      #pragma unroll
      for (int fd = 0; fd < 2; fd++) {
        const int row = fd * 16 + lr;
        vb[fd] = *(const bf16x8*)(VA + head * 4096 + row * 128 + ((c2 ^ (row & 7)) * 16));
      }
      #pragma unroll
      for (int fi = 0; fi < 4; fi++)
        #pragma unroll
        for (int fd = 0; fd < 2; fd++)
          o[fi][fd] = __builtin_amdgcn_mfma_f32_16x16x32_bf16(pa[fi], vb[fd], o[fi][fd], 0, 0, 0);
    }
  }
  __syncthreads();  // B4b: PV reads of V done -> O may overwrite VA

  if (wid < 6) {
    #pragma unroll
    for (int fi = 0; fi < 4; fi++)
      #pragma unroll
      for (int fd = 0; fd < 2; fd++)
        #pragma unroll
        for (int r = 0; r < 4; r++) {
          const int n = fi * 16 + lg * 4 + r;
          const int ch = head * 32 + fd * 16 + lr;
          const int p = ch >> 6, c = (ch >> 3) & 7;
          const int slot = c ^ (n & 7);
          *(unsigned short*)(VA + p * 8192 + n * 128 + slot * 16 + (ch & 7) * 2) =
              __builtin_bit_cast(unsigned short, __float2bfloat16(o[fi][fd][r]));
        }
  }
  __syncthreads();  // B5: O tile ready

  // ---- Phase 4: proj + gather residual -> hbuf ----
  {
    const int wrr2 = (wid >> 2) * 32, wcg2 = wid & 3;
    f32x4 accp[2][3];
    #pragma unroll
    for (int i = 0; i < 2; i++)
      #pragma unroll
      for (int j = 0; j < 3; j++) accp[i][j] = (f32x4){0.f, 0.f, 0.f, 0.f};
    #pragma unroll
    for (int kc = 0; kc < 6; kc++) {
      const int q = kc >> 1;
      const int kk = (kc & 1) * 4 + lg;
      bf16x8 af[2], bfr[3];
      #pragma unroll
      for (int i = 0; i < 2; i++) {
        const int row = wrr2 + i * 16 + lr;
        af[i] = *(const bf16x8*)(VA + q * 8192 + row * 128 + ((kk ^ (row & 7)) * 16));
      }
      #pragma unroll
      for (int j = 0; j < 3; j++)
        bfr[j] = *(const bf16x8*)(pwt + ((wcg2 * 3 + j) * 6 + kc) * 512 + lane * 8);
      #pragma unroll
      for (int i = 0; i < 2; i++)
        #pragma unroll
        for (int j = 0; j < 3; j++)
          accp[i][j] = __builtin_amdgcn_mfma_f32_16x16x32_bf16(af[i], bfr[j], accp[i][j], 0, 0, 0);
    }
    #pragma unroll
    for (int i = 0; i < 2; i++) {
      #pragma unroll
      for (int j = 0; j < 3; j++) {
        #pragma unroll
        for (int r = 0; r < 4; r++) {
          const long m = m0 + wrr2 + i * 16 + lg * 4 + r;
          const int cn = wcg2 * 48 + j * 16 + lr;
          const float v = accp[i][j][r] + pb[cn];
          const long b_ = m >> 6; const int n = (int)(m & 63);
          const int b = (int)(b_ >> 10), wk = (int)(b_ & 1023), wi = wk >> 5, wj = wk & 31;
          const int i_ = n >> 3, j_ = n & 7;
          const int hf = (wi * 8 + i_ + 4) & 255, wf = (wj * 8 + j_ + 4) & 255;
          const long g = (((long)b * 256 + hf) * 256 + wf) * 192 + cn;
          hbuf[g] = x[g] + v;   // h = shortcut + proj(attn)
        }
      }
    }
  }
}

// ------------ fused MLP v6 (R21-proven, ~340us): out = h + fc2(gelu(fc1(LN2(h)))) ------------
__global__ __launch_bounds__(512, 2) void mlp_fused(const float* __restrict__ hbuf,
                                                    const float* __restrict__ n2w,
                                                    const float* __restrict__ n2b,
                                                    const bf16* __restrict__ w1t,
                                                    const float* __restrict__ b1,
                                                    const bf16* __restrict__ w2t,
                                                    const float* __restrict__ b2,
                                                    float* __restrict__ outp) {
  __shared__ __align__(16) char smem[122880];
  char* Ab = smem;          // h_ln tile: 3 groups x [64 rows][8 slots][16B] = 24576
  char* G  = smem + 24576;  // g tile: [64 rows][96 slots][16B] = 98304

  const int tid = threadIdx.x;
  const long m0 = (long)blockIdx.x * 64;
  const int lane = tid & 63, wid = tid >> 6;
  const int lg = lane >> 4, lr = lane & 15;

  #pragma unroll
  for (int t8 = 0; t8 < 8; t8++) {
    const int row = wid * 8 + t8;
    const long g = (m0 + row) * 192;
    const float x0 = hbuf[g + lane], x1 = hbuf[g + 64 + lane], x2 = hbuf[g + 128 + lane];
    float s = x0 + x1 + x2;
    float s2 = x0 * x0 + x1 * x1 + x2 * x2;
    #pragma unroll
    for (int msk = 1; msk < 64; msk <<= 1) { s += __shfl_xor(s, msk); s2 += __shfl_xor(s2, msk); }
    const float mu = s * (1.0f / 192.0f);
    const float rstd = rsqrtf(s2 * (1.0f / 192.0f) - mu * mu + 1e-5f);
    #pragma unroll
    for (int p = 0; p < 3; p++) {
      const int ch = p * 64 + lane;
      const float xv = (p == 0) ? x0 : (p == 1) ? x1 : x2;
      const float v = (xv - mu) * rstd * n2w[ch] + n2b[ch];
      const int c = (ch >> 3) & 7;
      const int slot = c ^ (row & 7);
      *(unsigned short*)(Ab + p * 8192 + row * 128 + slot * 16 + (ch & 7) * 2) =
          __builtin_bit_cast(unsigned short, __float2bfloat16(v));
    }
  }
  __syncthreads();

  f32x4 acc1[4][6];
  #pragma unroll
  for (int i = 0; i < 4; i++)
    #pragma unroll
    for (int j = 0; j < 6; j++) acc1[i][j] = (f32x4){0.f, 0.f, 0.f, 0.f};

  const int c16base = wid * 6;
  #pragma unroll
  for (int kc = 0; kc < 6; kc++) {
    const int q = kc >> 1;
    const int kk = (kc & 1) * 4 + lg;
    bf16x8 af[4], bfr[6];
    #pragma unroll
    for (int i = 0; i < 4; i++) {
      const int row = i * 16 + lr;
      af[i] = *(const bf16x8*)(Ab + q * 8192 + row * 128 + ((kk ^ (row & 7)) * 16));
    }
    #pragma unroll
    for (int j = 0; j < 6; j++)
      bfr[j] = *(const bf16x8*)(w1t + ((c16base + j) * 6 + kc) * 512 + lane * 8);
    #pragma unroll
    for (int i = 0; i < 4; i++)
      #pragma unroll
      for (int j = 0; j < 6; j++)
        acc1[i][j] = __builtin_amdgcn_mfma_f32_16x16x32_bf16(af[i], bfr[j], acc1[i][j], 0, 0, 0);
  }

  #pragma unroll
  for (int j = 0; j < 6; j++) {
    const int n = wid * 96 + j * 16 + lr;
    const float bj = b1[n];
    const int c = n >> 3;
    #pragma unroll
    for (int i = 0; i < 4; i++) {
      #pragma unroll
      for (int r = 0; r < 4; r++) {
        const int m = i * 16 + lg * 4 + r;
        const int slot = (c & ~7) | ((c & 7) ^ (m & 7));
        *(unsigned short*)(G + m * 1536 + slot * 16 + (n & 7) * 2) =
            __builtin_bit_cast(unsigned short, __float2bfloat16(gelu_f(acc1[i][j][r] + bj)));
      }
    }
  }
  __syncthreads();

  const int wt = wid >> 2, wn = wid & 3;
  f32x4 acc2[2][3];
  #pragma unroll
  for (int i = 0; i < 2; i++)
    #pragma unroll
    for (int j = 0; j < 3; j++) acc2[i][j] = (f32x4){0.f, 0.f, 0.f, 0.f};

  for (int kt = 0; kt < 24; kt++) {
    const int c2 = kt * 4 + lg;
    bf16x8 af2[2], bfr2[3];
    #pragma unroll
    for (int i = 0; i < 2; i++) {
      const int grow = wt * 32 + i * 16 + lr;
      const int slot2 = (c2 & ~7) | ((c2 & 7) ^ (grow & 7));
      af2[i] = *(const bf16x8*)(G + grow * 1536 + slot2 * 16);
    }
    #pragma unroll
    for (int j = 0; j < 3; j++)
      bfr2[j] = *(const bf16x8*)(w2t + ((wn * 3 + j) * 24 + kt) * 512 + lane * 8);
    #pragma unroll
    for (int i = 0; i < 2; i++)
      #pragma unroll
      for (int j = 0; j < 3; j++)
        acc2[i][j] = __builtin_amdgcn_mfma_f32_16x16x32_bf16(af2[i], bfr2[j], acc2[i][j], 0, 0, 0);
  }

  #pragma unroll
  for (int j = 0; j < 3; j++) {
    const int cn = wn * 48 + j * 16 + lr;
    const float bj = b2[cn];
    #pragma unroll
    for (int i = 0; i < 2; i++) {
      #pragma unroll
      for (int r = 0; r < 4; r++) {
        const long m = m0 + wt * 32 + i * 16 + lg * 4 + r;
        outp[m * 192 + cn] = acc2[i][j][r] + bj + hbuf[m * 192 + cn];
      }
    }
  }
}

extern "C" void kernel_launch(void* const* d_in, const int* in_sizes, int n_in,
                              void* d_out, int out_size, void* d_ws, size_t ws_size,
                              hipStream_t stream) {
  const float* x      = (const float*)d_in[0];
  const float* qkv_w  = (const float*)d_in[1];
  const float* qkv_b  = (const float*)d_in[2];
  const float* proj_w = (const float*)d_in[3];
  const float* proj_b = (const float*)d_in[4];
  const float* rpb    = (const float*)d_in[5];
  const float* n1_w   = (const float*)d_in[6];
  const float* n1_b   = (const float*)d_in[7];
  const float* n2_w   = (const float*)d_in[8];
  const float* n2_b   = (const float*)d_in[9];
  const float* fc1_w  = (const float*)d_in[10];
  const float* fc1_b  = (const float*)d_in[11];
  const float* fc2_w  = (const float*)d_in[12];
  const float* fc2_b  = (const float*)d_in[13];

  char* ws = (char*)d_ws;
  // workspace: all weights fragment-order [0, 884736); hbuf at 1 MiB (+201.3 MB).
  bf16* qkvw_t  = (bf16*)(ws);
  bf16* projw_t = (bf16*)(ws + 221184);
  bf16* fc1w_t  = (bf16*)(ws + 294912);
  bf16* fc2w_t  = (bf16*)(ws + 589824);
  float* hbuf   = (float*)(ws + (1L << 20));

  cvt_frag_kernel<192, 6><<<432, 256, 0, stream>>>(qkv_w, qkvw_t, 110592);
  cvt_frag_kernel<192, 6><<<144, 256, 0, stream>>>(proj_w, projw_t, 36864);
  cvt_frag_kernel<192, 6><<<576, 256, 0, stream>>>(fc1_w, fc1w_t, 147456);
  cvt_frag_kernel<768, 24><<<576, 256, 0, stream>>>(fc2_w, fc2w_t, 147456);

  // fused LN1 + QKV + attention + proj + residual -> hbuf (one block per window)
  win_attn<<<4096, 512, 0, stream>>>(x, n1_w, n1_b, qkvw_t, qkv_b, rpb, projw_t, proj_b, hbuf);
  // fused LN2 + MLP: out = h + fc2(gelu(fc1(LN2(h))))
  mlp_fused<<<4096, 512, 0, stream>>>(hbuf, n2_w, n2_b, fc1w_t, fc1_b, fc2w_t, fc2_b,
                                      (float*)d_out);
}

// Round 23
// 795.020 us; speedup vs baseline: 1.0192x; 1.0192x over previous
//
#include <hip/hip_runtime.h>
#include <hip/hip_bf16.h>

typedef __attribute__((ext_vector_type(8))) __bf16 bf16x8;
typedef __attribute__((ext_vector_type(4))) float f32x4;
typedef __hip_bfloat16 bf16;

#define SCALE_Q 0.17677669529663687f

// exact-grade GELU: Abramowitz-Stegun 7.1.26 erf (|err| < 1.5e-7)
__device__ inline float gelu_f(float x) {
  const float ax = fabsf(x) * 0.70710678118654752f;
  const float t = __builtin_amdgcn_rcpf(__builtin_fmaf(0.3275911f, ax, 1.0f));
  const float poly = t * __builtin_fmaf(t, __builtin_fmaf(t, __builtin_fmaf(t,
                     __builtin_fmaf(t, 1.061405429f, -1.453152027f),
                     1.421413741f), -0.284496736f), 0.254829592f);
  const float er = __builtin_fmaf(-poly, __expf(-ax * ax), 1.0f);
  return 0.5f * x * (1.0f + copysignf(er, x));
}

// ---- weight fp32 -> bf16 in MFMA B-fragment order ----
// src [N][K] row-major; dst chunk (n>>4, k>>5) holds [lg=(k>>3)&3][lr=n&15][e=k&7].
template<int K, int KC>
__global__ void cvt_frag_kernel(const float* __restrict__ in, bf16* __restrict__ out, int total) {
  int i = blockIdx.x * 256 + threadIdx.x;
  if (i < total) {
    const int n = i / K, k = i - n * K;
    out[((n >> 4) * KC + (k >> 5)) * 512 + ((k >> 3) & 3) * 128 + (n & 15) * 8 + (k & 7)] =
        __float2bfloat16(in[i]);
  }
}

// ===== window mega-kernel (R21-best, 447us): LN1+QKV+attention+proj+residual -> hbuf =====
__global__ __launch_bounds__(512, 2) void win_attn(const float* __restrict__ x,
                                                   const float* __restrict__ n1w,
                                                   const float* __restrict__ n1b,
                                                   const bf16* __restrict__ qwt,
                                                   const float* __restrict__ qb,
                                                   const float* __restrict__ rpb,
                                                   const bf16* __restrict__ pwt,
                                                   const float* __restrict__ pb,
                                                   float* __restrict__ hbuf) {
  __shared__ __align__(16) char smem[119072];
  char* Qt = smem;                        // 6 heads x 5120 = 30720  (P overlays Q+K later)
  char* Kt = smem + 30720;                // 30720
  char* Vtb = smem + 61440;               // 6 x 4608 = 27648
  char* Ab = smem + 89088;                // 24576: LN1 tile, later O tile
  float* rpl = (float*)(smem + 113664);   // 6 x 225 floats = 5400

  const int tid = threadIdx.x;
  const int blk = blockIdx.x;             // window index b_
  const long m0 = (long)blk * 64;
  const int lane = tid & 63, wid = tid >> 6;
  const int lg = lane >> 4, lr = lane & 15;

  for (int t = tid; t < 1350; t += 512) {
    const int hh = t / 225, tt = t - hh * 225;
    rpl[hh * 225 + tt] = rpb[tt * 6 + hh];
  }

  // ---- Phase 1: LN1 + shifted-window gather -> Ab ----
  #pragma unroll
  for (int t8 = 0; t8 < 8; t8++) {
    const int row = wid * 8 + t8;
    const long t = m0 + row;
    const int b_ = (int)(t >> 6), n = (int)(t & 63);
    const int b = b_ >> 10, wk = b_ & 1023, wi = wk >> 5, wj = wk & 31;
    const int hf = (wi * 8 + (n >> 3) + 4) & 255, wf = (wj * 8 + (n & 7) + 4) & 255;
    const long g = (((long)b * 256 + hf) * 256 + wf) * 192;
    const float x0 = x[g + lane], x1 = x[g + 64 + lane], x2 = x[g + 128 + lane];
    float s = x0 + x1 + x2;
    float s2 = x0 * x0 + x1 * x1 + x2 * x2;
    #pragma unroll
    for (int msk = 1; msk < 64; msk <<= 1) { s += __shfl_xor(s, msk); s2 += __shfl_xor(s2, msk); }
    const float mu = s * (1.0f / 192.0f);
    const float rstd = rsqrtf(s2 * (1.0f / 192.0f) - mu * mu + 1e-5f);
    #pragma unroll
    for (int p = 0; p < 3; p++) {
      const int ch = p * 64 + lane;
      const float xv = (p == 0) ? x0 : (p == 1) ? x1 : x2;
      const float v = (xv - mu) * rstd * n1w[ch] + n1b[ch];
      const int c = (ch >> 3) & 7;
      const int slot = c ^ (row & 7);
      *(unsigned short*)(Ab + p * 8192 + row * 128 + slot * 16 + (ch & 7) * 2) =
          __builtin_bit_cast(unsigned short, __float2bfloat16(v));
    }
  }
  __syncthreads();  // B1

  // ---- Phase 2: QKV GEMM, epilogue -> LDS Q/K/Vt ----
  {
    const int wrr = (wid >> 2) * 32;
    const int wcg = wid & 3;
    f32x4 acc[2][9];
    #pragma unroll
    for (int i = 0; i < 2; i++)
      #pragma unroll
      for (int j = 0; j < 9; j++) acc[i][j] = (f32x4){0.f, 0.f, 0.f, 0.f};
    const int c16base = wcg * 9;
    #pragma unroll
    for (int kc = 0; kc < 6; kc++) {
      const int q = kc >> 1;
      const int kk = (kc & 1) * 4 + lg;
      bf16x8 af[2], bfr[9];
      #pragma unroll
      for (int i = 0; i < 2; i++) {
        const int row = wrr + i * 16 + lr;
        af[i] = *(const bf16x8*)(Ab + q * 8192 + row * 128 + ((kk ^ (row & 7)) * 16));
      }
      #pragma unroll
      for (int j = 0; j < 9; j++)
        bfr[j] = *(const bf16x8*)(qwt + ((c16base + j) * 6 + kc) * 512 + lane * 8);
      #pragma unroll
      for (int i = 0; i < 2; i++)
        #pragma unroll
        for (int j = 0; j < 9; j++)
          acc[i][j] = __builtin_amdgcn_mfma_f32_16x16x32_bf16(af[i], bfr[j], acc[i][j], 0, 0, 0);
    }
    #pragma unroll
    for (int i = 0; i < 2; i++) {
      #pragma unroll
      for (int j = 0; j < 9; j++) {
        #pragma unroll
        for (int r = 0; r < 4; r++) {
          const int n = wrr + i * 16 + lg * 4 + r;
          const int cn = wcg * 144 + j * 16 + lr;
          float v = acc[i][j][r] + qb[cn];
          const int which = cn / 192, rem = cn - which * 192, head = rem >> 5, d = rem & 31;
          unsigned short us;
          if (which == 0) { v *= SCALE_Q; us = __builtin_bit_cast(unsigned short, __float2bfloat16(v));
            *(unsigned short*)(Qt + head * 5120 + n * 80 + d * 2) = us; }
          else if (which == 1) { us = __builtin_bit_cast(unsigned short, __float2bfloat16(v));
            *(unsigned short*)(Kt + head * 5120 + n * 80 + d * 2) = us; }
          else { us = __builtin_bit_cast(unsigned short, __float2bfloat16(v));
            *(unsigned short*)(Vtb + head * 4608 + (d * 72 + n) * 2) = us; }
        }
      }
    }
  }
  __syncthreads();  // B2

  // ---- Phase 3: attention (head = wid for wid<6) ----
  const f32x4 z4 = {0.f, 0.f, 0.f, 0.f};
  f32x4 s[4][4];
  const int head = wid;
  if (wid < 6) {
    bf16x8 a[4], b[4];
    #pragma unroll
    for (int fi = 0; fi < 4; fi++)
      a[fi] = *(const bf16x8*)(Qt + head * 5120 + (fi * 16 + lr) * 80 + lg * 16);
    #pragma unroll
    for (int fj = 0; fj < 4; fj++)
      b[fj] = *(const bf16x8*)(Kt + head * 5120 + (fj * 16 + lr) * 80 + lg * 16);
    #pragma unroll
    for (int fi = 0; fi < 4; fi++)
      #pragma unroll
      for (int fj = 0; fj < 4; fj++)
        s[fi][fj] = __builtin_amdgcn_mfma_f32_16x16x32_bf16(a[fi], b[fj], z4, 0, 0, 0);
  }
  __syncthreads();  // B3

  bf16* P = (bf16*)(smem + head * 9216);
  if (wid < 6) {
    const int wk = blk & 1023; const int wi = wk >> 5, wj = wk & 31;
    const bool eh = (wi == 31), ew = (wj == 31);
    const float* rps = rpl + head * 225;
    #pragma unroll
    for (int fi = 0; fi < 4; fi++) {
      #pragma unroll
      for (int r = 0; r < 4; r++) {
        const int n = fi * 16 + lg * 4 + r;
        const int i1 = n >> 3, j1 = n & 7;
        const int labn = (eh ? (i1 < 4 ? 3 : 6) : 0) + (ew ? (j1 < 4 ? 1 : 2) : 0);
        float vals[4];
        #pragma unroll
        for (int fj = 0; fj < 4; fj++) {
          const int m = fj * 16 + lr;
          const int i2 = m >> 3, j2 = m & 7;
          const int labm = (eh ? (i2 < 4 ? 3 : 6) : 0) + (ew ? (j2 < 4 ? 1 : 2) : 0);
          vals[fj] = s[fi][fj][r] + rps[(i1 - i2 + 7) * 15 + (j1 - j2 + 7)]
                   + (labn != labm ? -100.0f : 0.0f);
        }
        float mx = fmaxf(fmaxf(vals[0], vals[1]), fmaxf(vals[2], vals[3]));
        #pragma unroll
        for (int msk = 1; msk < 16; msk <<= 1) mx = fmaxf(mx, __shfl_xor(mx, msk));
        float pe[4]; float sum = 0.f;
        #pragma unroll
        for (int fj = 0; fj < 4; fj++) { pe[fj] = __expf(vals[fj] - mx); sum += pe[fj]; }
        #pragma unroll
        for (int msk = 1; msk < 16; msk <<= 1) sum += __shfl_xor(sum, msk);
        const float rinv = 1.0f / sum;
        #pragma unroll
        for (int fj = 0; fj < 4; fj++)
          P[n * 72 + fj * 16 + lr] = __float2bfloat16(pe[fj] * rinv);
      }
    }
  }
  __syncthreads();  // B4

  if (wid < 6) {
    f32x4 o[4][2];
    #pragma unroll
    for (int fi = 0; fi < 4; fi++)
      #pragma unroll
      for (int fd = 0; fd < 2; fd++) o[fi][fd] = z4;
    const bf16* vt = (const bf16*)(Vtb + head * 4608);
    #pragma unroll
    for (int ks = 0; ks < 2; ks++) {
      bf16x8 pa[4], vb[2];
      #pragma unroll
      for (int fi = 0; fi < 4; fi++)
        pa[fi] = *(const bf16x8*)(P + (fi * 16 + lr) * 72 + ks * 32 + lg * 8);
      #pragma unroll
      for (int fd = 0; fd < 2; fd++)
        vb[fd] = *(const bf16x8*)(vt + (fd * 16 + lr) * 72 + ks * 32 + lg * 8);
      #pragma unroll
      for (int fi = 0; fi < 4; fi++)
        #pragma unroll
        for (int fd = 0; fd < 2; fd++)
          o[fi][fd] = __builtin_amdgcn_mfma_f32_16x16x32_bf16(pa[fi], vb[fd], o[fi][fd], 0, 0, 0);
    }
    #pragma unroll
    for (int fi = 0; fi < 4; fi++)
      #pragma unroll
      for (int fd = 0; fd < 2; fd++)
        #pragma unroll
        for (int r = 0; r < 4; r++) {
          const int n = fi * 16 + lg * 4 + r;
          const int ch = head * 32 + fd * 16 + lr;
          const int p = ch >> 6, c = (ch >> 3) & 7;
          const int slot = c ^ (n & 7);
          *(unsigned short*)(Ab + p * 8192 + n * 128 + slot * 16 + (ch & 7) * 2) =
              __builtin_bit_cast(unsigned short, __float2bfloat16(o[fi][fd][r]));
        }
  }
  __syncthreads();  // B5

  // ---- Phase 4: proj + gather residual -> hbuf ----
  {
    const int wrr2 = (wid >> 2) * 32, wcg2 = wid & 3;
    f32x4 accp[2][3];
    #pragma unroll
    for (int i = 0; i < 2; i++)
      #pragma unroll
      for (int j = 0; j < 3; j++) accp[i][j] = (f32x4){0.f, 0.f, 0.f, 0.f};
    #pragma unroll
    for (int kc = 0; kc < 6; kc++) {
      const int q = kc >> 1;
      const int kk = (kc & 1) * 4 + lg;
      bf16x8 af[2], bfr[3];
      #pragma unroll
      for (int i = 0; i < 2; i++) {
        const int row = wrr2 + i * 16 + lr;
        af[i] = *(const bf16x8*)(Ab + q * 8192 + row * 128 + ((kk ^ (row & 7)) * 16));
      }
      #pragma unroll
      for (int j = 0; j < 3; j++)
        bfr[j] = *(const bf16x8*)(pwt + ((wcg2 * 3 + j) * 6 + kc) * 512 + lane * 8);
      #pragma unroll
      for (int i = 0; i < 2; i++)
        #pragma unroll
        for (int j = 0; j < 3; j++)
          accp[i][j] = __builtin_amdgcn_mfma_f32_16x16x32_bf16(af[i], bfr[j], accp[i][j], 0, 0, 0);
    }
    #pragma unroll
    for (int i = 0; i < 2; i++) {
      #pragma unroll
      for (int j = 0; j < 3; j++) {
        #pragma unroll
        for (int r = 0; r < 4; r++) {
          const long m = m0 + wrr2 + i * 16 + lg * 4 + r;
          const int cn = wcg2 * 48 + j * 16 + lr;
          const float v = accp[i][j][r] + pb[cn];
          const long b_ = m >> 6; const int n = (int)(m & 63);
          const int b = (int)(b_ >> 10), wk = (int)(b_ & 1023), wi = wk >> 5, wj = wk & 31;
          const int i_ = n >> 3, j_ = n & 7;
          const int hf = (wi * 8 + i_ + 4) & 255, wf = (wj * 8 + j_ + 4) & 255;
          const long g = (((long)b * 256 + hf) * 256 + wf) * 192 + cn;
          hbuf[g] = x[g] + v;   // h = shortcut + proj(attn)
        }
      }
    }
  }
}

// ------------ fused MLP v6 (R21-proven, ~340us): out = h + fc2(gelu(fc1(LN2(h)))) ------------
__global__ __launch_bounds__(512, 2) void mlp_fused(const float* __restrict__ hbuf,
                                                    const float* __restrict__ n2w,
                                                    const float* __restrict__ n2b,
                                                    const bf16* __restrict__ w1t,
                                                    const float* __restrict__ b1,
                                                    const bf16* __restrict__ w2t,
                                                    const float* __restrict__ b2,
                                                    float* __restrict__ outp) {
  __shared__ __align__(16) char smem[122880];
  char* Ab = smem;          // h_ln tile: 3 groups x [64 rows][8 slots][16B] = 24576
  char* G  = smem + 24576;  // g tile: [64 rows][96 slots][16B] = 98304

  const int tid = threadIdx.x;
  const long m0 = (long)blockIdx.x * 64;
  const int lane = tid & 63, wid = tid >> 6;
  const int lg = lane >> 4, lr = lane & 15;

  #pragma unroll
  for (int t8 = 0; t8 < 8; t8++) {
    const int row = wid * 8 + t8;
    const long g = (m0 + row) * 192;
    const float x0 = hbuf[g + lane], x1 = hbuf[g + 64 + lane], x2 = hbuf[g + 128 + lane];
    float s = x0 + x1 + x2;
    float s2 = x0 * x0 + x1 * x1 + x2 * x2;
    #pragma unroll
    for (int msk = 1; msk < 64; msk <<= 1) { s += __shfl_xor(s, msk); s2 += __shfl_xor(s2, msk); }
    const float mu = s * (1.0f / 192.0f);
    const float rstd = rsqrtf(s2 * (1.0f / 192.0f) - mu * mu + 1e-5f);
    #pragma unroll
    for (int p = 0; p < 3; p++) {
      const int ch = p * 64 + lane;
      const float xv = (p == 0) ? x0 : (p == 1) ? x1 : x2;
      const float v = (xv - mu) * rstd * n2w[ch] + n2b[ch];
      const int c = (ch >> 3) & 7;
      const int slot = c ^ (row & 7);
      *(unsigned short*)(Ab + p * 8192 + row * 128 + slot * 16 + (ch & 7) * 2) =
          __builtin_bit_cast(unsigned short, __float2bfloat16(v));
    }
  }
  __syncthreads();

  f32x4 acc1[4][6];
  #pragma unroll
  for (int i = 0; i < 4; i++)
    #pragma unroll
    for (int j = 0; j < 6; j++) acc1[i][j] = (f32x4){0.f, 0.f, 0.f, 0.f};

  const int c16base = wid * 6;
  #pragma unroll
  for (int kc = 0; kc < 6; kc++) {
    const int q = kc >> 1;
    const int kk = (kc & 1) * 4 + lg;
    bf16x8 af[4], bfr[6];
    #pragma unroll
    for (int i = 0; i < 4; i++) {
      const int row = i * 16 + lr;
      af[i] = *(const bf16x8*)(Ab + q * 8192 + row * 128 + ((kk ^ (row & 7)) * 16));
    }
    #pragma unroll
    for (int j = 0; j < 6; j++)
      bfr[j] = *(const bf16x8*)(w1t + ((c16base + j) * 6 + kc) * 512 + lane * 8);
    #pragma unroll
    for (int i = 0; i < 4; i++)
      #pragma unroll
      for (int j = 0; j < 6; j++)
        acc1[i][j] = __builtin_amdgcn_mfma_f32_16x16x32_bf16(af[i], bfr[j], acc1[i][j], 0, 0, 0);
  }

  #pragma unroll
  for (int j = 0; j < 6; j++) {
    const int n = wid * 96 + j * 16 + lr;
    const float bj = b1[n];
    const int c = n >> 3;
    #pragma unroll
    for (int i = 0; i < 4; i++) {
      #pragma unroll
      for (int r = 0; r < 4; r++) {
        const int m = i * 16 + lg * 4 + r;
        const int slot = (c & ~7) | ((c & 7) ^ (m & 7));
        *(unsigned short*)(G + m * 1536 + slot * 16 + (n & 7) * 2) =
            __builtin_bit_cast(unsigned short, __float2bfloat16(gelu_f(acc1[i][j][r] + bj)));
      }
    }
  }
  __syncthreads();

  const int wt = wid >> 2, wn = wid & 3;
  f32x4 acc2[2][3];
  #pragma unroll
  for (int i = 0; i < 2; i++)
    #pragma unroll
    for (int j = 0; j < 3; j++) acc2[i][j] = (f32x4){0.f, 0.f, 0.f, 0.f};

  for (int kt = 0; kt < 24; kt++) {
    const int c2 = kt * 4 + lg;
    bf16x8 af2[2], bfr2[3];
    #pragma unroll
    for (int i = 0; i < 2; i++) {
      const int grow = wt * 32 + i * 16 + lr;
      const int slot2 = (c2 & ~7) | ((c2 & 7) ^ (grow & 7));
      af2[i] = *(const bf16x8*)(G + grow * 1536 + slot2 * 16);
    }
    #pragma unroll
    for (int j = 0; j < 3; j++)
      bfr2[j] = *(const bf16x8*)(w2t + ((wn * 3 + j) * 24 + kt) * 512 + lane * 8);
    #pragma unroll
    for (int i = 0; i < 2; i++)
      #pragma unroll
      for (int j = 0; j < 3; j++)
        acc2[i][j] = __builtin_amdgcn_mfma_f32_16x16x32_bf16(af2[i], bfr2[j], acc2[i][j], 0, 0, 0);
  }

  #pragma unroll
  for (int j = 0; j < 3; j++) {
    const int cn = wn * 48 + j * 16 + lr;
    const float bj = b2[cn];
    #pragma unroll
    for (int i = 0; i < 2; i++) {
      #pragma unroll
      for (int r = 0; r < 4; r++) {
        const long m = m0 + wt * 32 + i * 16 + lg * 4 + r;
        outp[m * 192 + cn] = acc2[i][j][r] + bj + hbuf[m * 192 + cn];
      }
    }
  }
}

extern "C" void kernel_launch(void* const* d_in, const int* in_sizes, int n_in,
                              void* d_out, int out_size, void* d_ws, size_t ws_size,
                              hipStream_t stream) {
  const float* x      = (const float*)d_in[0];
  const float* qkv_w  = (const float*)d_in[1];
  const float* qkv_b  = (const float*)d_in[2];
  const float* proj_w = (const float*)d_in[3];
  const float* proj_b = (const float*)d_in[4];
  const float* rpb    = (const float*)d_in[5];
  const float* n1_w   = (const float*)d_in[6];
  const float* n1_b   = (const float*)d_in[7];
  const float* n2_w   = (const float*)d_in[8];
  const float* n2_b   = (const float*)d_in[9];
  const float* fc1_w  = (const float*)d_in[10];
  const float* fc1_b  = (const float*)d_in[11];
  const float* fc2_w  = (const float*)d_in[12];
  const float* fc2_b  = (const float*)d_in[13];

  char* ws = (char*)d_ws;
  // workspace: all weights fragment-order [0, 884736); hbuf at 1 MiB (+201.3 MB).
  bf16* qkvw_t  = (bf16*)(ws);
  bf16* projw_t = (bf16*)(ws + 221184);
  bf16* fc1w_t  = (bf16*)(ws + 294912);
  bf16* fc2w_t  = (bf16*)(ws + 589824);
  float* hbuf   = (float*)(ws + (1L << 20));

  cvt_frag_kernel<192, 6><<<432, 256, 0, stream>>>(qkv_w, qkvw_t, 110592);
  cvt_frag_kernel<192, 6><<<144, 256, 0, stream>>>(proj_w, projw_t, 36864);
  cvt_frag_kernel<192, 6><<<576, 256, 0, stream>>>(fc1_w, fc1w_t, 147456);
  cvt_frag_kernel<768, 24><<<576, 256, 0, stream>>>(fc2_w, fc2w_t, 147456);

  // fused LN1 + QKV + attention + proj + residual -> hbuf (one block per window)
  win_attn<<<4096, 512, 0, stream>>>(x, n1_w, n1_b, qkvw_t, qkv_b, rpb, projw_t, proj_b, hbuf);
  // fused LN2 + MLP: out = h + fc2(gelu(fc1(LN2(h))))
  mlp_fused<<<4096, 512, 0, stream>>>(hbuf, n2_w, n2_b, fc1w_t, fc1_b, fc2w_t, fc2_b,
                                      (float*)d_out);
}

// Round 24
// 778.681 us; speedup vs baseline: 1.0406x; 1.0210x over previous
//
#include <hip/hip_runtime.h>
#include <hip/hip_bf16.h>

typedef __attribute__((ext_vector_type(8))) __bf16 bf16x8;
typedef __attribute__((ext_vector_type(4))) float f32x4;
typedef __hip_bfloat16 bf16;

#define SCALE_Q 0.17677669529663687f

// exact-grade GELU: Abramowitz-Stegun 7.1.26 erf (|err| < 1.5e-7)
__device__ inline float gelu_f(float x) {
  const float ax = fabsf(x) * 0.70710678118654752f;
  const float t = __builtin_amdgcn_rcpf(__builtin_fmaf(0.3275911f, ax, 1.0f));
  const float poly = t * __builtin_fmaf(t, __builtin_fmaf(t, __builtin_fmaf(t,
                     __builtin_fmaf(t, 1.061405429f, -1.453152027f),
                     1.421413741f), -0.284496736f), 0.254829592f);
  const float er = __builtin_fmaf(-poly, __expf(-ax * ax), 1.0f);
  return 0.5f * x * (1.0f + copysignf(er, x));
}

// ---- weight fp32 -> bf16 in MFMA B-fragment order ----
// src [N][K] row-major; dst chunk (n>>4, k>>5) holds [lg=(k>>3)&3][lr=n&15][e=k&7].
template<int K, int KC>
__global__ void cvt_frag_kernel(const float* __restrict__ in, bf16* __restrict__ out, int total) {
  int i = blockIdx.x * 256 + threadIdx.x;
  if (i < total) {
    const int n = i / K, k = i - n * K;
    out[((n >> 4) * KC + (k >> 5)) * 512 + ((k >> 3) & 3) * 128 + (n & 15) * 8 + (k & 7)] =
        __float2bfloat16(in[i]);
  }
}

// ===== window mega-kernel: LN1+QKV+attention+proj+residual -> hbuf =====
// R21 structure; attention phases rebalanced to 24 tasks (6 heads x 4 row-blocks)
// over all 8 waves (was 6 waves + 2 idle). Per-row math identical.
__global__ __launch_bounds__(512, 2) void win_attn(const float* __restrict__ x,
                                                   const float* __restrict__ n1w,
                                                   const float* __restrict__ n1b,
                                                   const bf16* __restrict__ qwt,
                                                   const float* __restrict__ qb,
                                                   const float* __restrict__ rpb,
                                                   const bf16* __restrict__ pwt,
                                                   const float* __restrict__ pb,
                                                   float* __restrict__ hbuf) {
  __shared__ __align__(16) char smem[119072];
  char* Qt = smem;                        // 6 heads x 5120 = 30720  (P overlays Q+K later)
  char* Kt = smem + 30720;                // 30720
  char* Vtb = smem + 61440;               // 6 x 4608 = 27648
  char* Ab = smem + 89088;                // 24576: LN1 tile, later O tile
  float* rpl = (float*)(smem + 113664);   // 6 x 225 floats = 5400

  const int tid = threadIdx.x;
  const int blk = blockIdx.x;             // window index b_
  const long m0 = (long)blk * 64;
  const int lane = tid & 63, wid = tid >> 6;
  const int lg = lane >> 4, lr = lane & 15;

  for (int t = tid; t < 1350; t += 512) {
    const int hh = t / 225, tt = t - hh * 225;
    rpl[hh * 225 + tt] = rpb[tt * 6 + hh];
  }

  // ---- Phase 1: LN1 + shifted-window gather -> Ab ----
  #pragma unroll
  for (int t8 = 0; t8 < 8; t8++) {
    const int row = wid * 8 + t8;
    const long t = m0 + row;
    const int b_ = (int)(t >> 6), n = (int)(t & 63);
    const int b = b_ >> 10, wk = b_ & 1023, wi = wk >> 5, wj = wk & 31;
    const int hf = (wi * 8 + (n >> 3) + 4) & 255, wf = (wj * 8 + (n & 7) + 4) & 255;
    const long g = (((long)b * 256 + hf) * 256 + wf) * 192;
    const float x0 = x[g + lane], x1 = x[g + 64 + lane], x2 = x[g + 128 + lane];
    float s = x0 + x1 + x2;
    float s2 = x0 * x0 + x1 * x1 + x2 * x2;
    #pragma unroll
    for (int msk = 1; msk < 64; msk <<= 1) { s += __shfl_xor(s, msk); s2 += __shfl_xor(s2, msk); }
    const float mu = s * (1.0f / 192.0f);
    const float rstd = rsqrtf(s2 * (1.0f / 192.0f) - mu * mu + 1e-5f);
    #pragma unroll
    for (int p = 0; p < 3; p++) {
      const int ch = p * 64 + lane;
      const float xv = (p == 0) ? x0 : (p == 1) ? x1 : x2;
      const float v = (xv - mu) * rstd * n1w[ch] + n1b[ch];
      const int c = (ch >> 3) & 7;
      const int slot = c ^ (row & 7);
      *(unsigned short*)(Ab + p * 8192 + row * 128 + slot * 16 + (ch & 7) * 2) =
          __builtin_bit_cast(unsigned short, __float2bfloat16(v));
    }
  }
  __syncthreads();  // B1

  // ---- Phase 2: QKV GEMM, epilogue -> LDS Q/K/Vt ----
  {
    const int wrr = (wid >> 2) * 32;
    const int wcg = wid & 3;
    f32x4 acc[2][9];
    #pragma unroll
    for (int i = 0; i < 2; i++)
      #pragma unroll
      for (int j = 0; j < 9; j++) acc[i][j] = (f32x4){0.f, 0.f, 0.f, 0.f};
    const int c16base = wcg * 9;
    #pragma unroll
    for (int kc = 0; kc < 6; kc++) {
      const int q = kc >> 1;
      const int kk = (kc & 1) * 4 + lg;
      bf16x8 af[2], bfr[9];
      #pragma unroll
      for (int i = 0; i < 2; i++) {
        const int row = wrr + i * 16 + lr;
        af[i] = *(const bf16x8*)(Ab + q * 8192 + row * 128 + ((kk ^ (row & 7)) * 16));
      }
      #pragma unroll
      for (int j = 0; j < 9; j++)
        bfr[j] = *(const bf16x8*)(qwt + ((c16base + j) * 6 + kc) * 512 + lane * 8);
      #pragma unroll
      for (int i = 0; i < 2; i++)
        #pragma unroll
        for (int j = 0; j < 9; j++)
          acc[i][j] = __builtin_amdgcn_mfma_f32_16x16x32_bf16(af[i], bfr[j], acc[i][j], 0, 0, 0);
    }
    #pragma unroll
    for (int i = 0; i < 2; i++) {
      #pragma unroll
      for (int j = 0; j < 9; j++) {
        #pragma unroll
        for (int r = 0; r < 4; r++) {
          const int n = wrr + i * 16 + lg * 4 + r;
          const int cn = wcg * 144 + j * 16 + lr;
          float v = acc[i][j][r] + qb[cn];
          const int which = cn / 192, rem = cn - which * 192, head = rem >> 5, d = rem & 31;
          unsigned short us;
          if (which == 0) { v *= SCALE_Q; us = __builtin_bit_cast(unsigned short, __float2bfloat16(v));
            *(unsigned short*)(Qt + head * 5120 + n * 80 + d * 2) = us; }
          else if (which == 1) { us = __builtin_bit_cast(unsigned short, __float2bfloat16(v));
            *(unsigned short*)(Kt + head * 5120 + n * 80 + d * 2) = us; }
          else { us = __builtin_bit_cast(unsigned short, __float2bfloat16(v));
            *(unsigned short*)(Vtb + head * 4608 + (d * 72 + n) * 2) = us; }
        }
      }
    }
  }
  __syncthreads();  // B2: Q/K/Vt ready

  // ---- Phase 3: attention, 24 tasks (head = task>>2, row-block rb = task&3) ----
  const f32x4 z4 = {0.f, 0.f, 0.f, 0.f};
  f32x4 sx[3][4];
  #pragma unroll
  for (int t = 0; t < 3; t++) {
    const int task = wid + t * 8;
    const int th = task >> 2, rb = task & 3;
    bf16x8 a, b[4];
    a = *(const bf16x8*)(Qt + th * 5120 + (rb * 16 + lr) * 80 + lg * 16);
    #pragma unroll
    for (int fj = 0; fj < 4; fj++)
      b[fj] = *(const bf16x8*)(Kt + th * 5120 + (fj * 16 + lr) * 80 + lg * 16);
    #pragma unroll
    for (int fj = 0; fj < 4; fj++)
      sx[t][fj] = __builtin_amdgcn_mfma_f32_16x16x32_bf16(a, b[fj], z4, 0, 0, 0);
  }
  __syncthreads();  // B3: all Q/K reads done before P overlays them

  {
    const int wk = blk & 1023; const int wi = wk >> 5, wj = wk & 31;
    const bool eh = (wi == 31), ew = (wj == 31);
    #pragma unroll
    for (int t = 0; t < 3; t++) {
      const int task = wid + t * 8;
      const int th = task >> 2, rb = task & 3;
      bf16* P = (bf16*)(smem + th * 9216);
      const float* rps = rpl + th * 225;
      #pragma unroll
      for (int r = 0; r < 4; r++) {
        const int n = rb * 16 + lg * 4 + r;
        const int i1 = n >> 3, j1 = n & 7;
        const int labn = (eh ? (i1 < 4 ? 3 : 6) : 0) + (ew ? (j1 < 4 ? 1 : 2) : 0);
        float vals[4];
        #pragma unroll
        for (int fj = 0; fj < 4; fj++) {
          const int m = fj * 16 + lr;
          const int i2 = m >> 3, j2 = m & 7;
          const int labm = (eh ? (i2 < 4 ? 3 : 6) : 0) + (ew ? (j2 < 4 ? 1 : 2) : 0);
          vals[fj] = sx[t][fj][r] + rps[(i1 - i2 + 7) * 15 + (j1 - j2 + 7)]
                   + (labn != labm ? -100.0f : 0.0f);
        }
        float mx = fmaxf(fmaxf(vals[0], vals[1]), fmaxf(vals[2], vals[3]));
        #pragma unroll
        for (int msk = 1; msk < 16; msk <<= 1) mx = fmaxf(mx, __shfl_xor(mx, msk));
        float pe[4]; float sum = 0.f;
        #pragma unroll
        for (int fj = 0; fj < 4; fj++) { pe[fj] = __expf(vals[fj] - mx); sum += pe[fj]; }
        #pragma unroll
        for (int msk = 1; msk < 16; msk <<= 1) sum += __shfl_xor(sum, msk);
        const float rinv = 1.0f / sum;
        #pragma unroll
        for (int fj = 0; fj < 4; fj++)
          P[n * 72 + fj * 16 + lr] = __float2bfloat16(pe[fj] * rinv);
      }
    }
  }
  __syncthreads();  // B4: P ready

  {
    f32x4 o[3][2];
    #pragma unroll
    for (int t = 0; t < 3; t++) {
      const int task = wid + t * 8;
      const int th = task >> 2, rb = task & 3;
      const bf16* P = (const bf16*)(smem + th * 9216);
      const bf16* vt = (const bf16*)(Vtb + th * 4608);
      o[t][0] = z4; o[t][1] = z4;
      #pragma unroll
      for (int ks = 0; ks < 2; ks++) {
        const bf16x8 pa = *(const bf16x8*)(P + (rb * 16 + lr) * 72 + ks * 32 + lg * 8);
        #pragma unroll
        for (int fd = 0; fd < 2; fd++) {
          const bf16x8 vb = *(const bf16x8*)(vt + (fd * 16 + lr) * 72 + ks * 32 + lg * 8);
          o[t][fd] = __builtin_amdgcn_mfma_f32_16x16x32_bf16(pa, vb, o[t][fd], 0, 0, 0);
        }
      }
    }
    // O -> Ab-format tile (Ab dead since B2)
    #pragma unroll
    for (int t = 0; t < 3; t++) {
      const int task = wid + t * 8;
      const int th = task >> 2, rb = task & 3;
      #pragma unroll
      for (int fd = 0; fd < 2; fd++)
        #pragma unroll
        for (int r = 0; r < 4; r++) {
          const int n = rb * 16 + lg * 4 + r;
          const int ch = th * 32 + fd * 16 + lr;
          const int p = ch >> 6, c = (ch >> 3) & 7;
          const int slot = c ^ (n & 7);
          *(unsigned short*)(Ab + p * 8192 + n * 128 + slot * 16 + (ch & 7) * 2) =
              __builtin_bit_cast(unsigned short, __float2bfloat16(o[t][fd][r]));
        }
    }
  }
  __syncthreads();  // B5: O tile ready

  // ---- Phase 4: proj + gather residual -> hbuf ----
  {
    const int wrr2 = (wid >> 2) * 32, wcg2 = wid & 3;
    f32x4 accp[2][3];
    #pragma unroll
    for (int i = 0; i < 2; i++)
      #pragma unroll
      for (int j = 0; j < 3; j++) accp[i][j] = (f32x4){0.f, 0.f, 0.f, 0.f};
    #pragma unroll
    for (int kc = 0; kc < 6; kc++) {
      const int q = kc >> 1;
      const int kk = (kc & 1) * 4 + lg;
      bf16x8 af[2], bfr[3];
      #pragma unroll
      for (int i = 0; i < 2; i++) {
        const int row = wrr2 + i * 16 + lr;
        af[i] = *(const bf16x8*)(Ab + q * 8192 + row * 128 + ((kk ^ (row & 7)) * 16));
      }
      #pragma unroll
      for (int j = 0; j < 3; j++)
        bfr[j] = *(const bf16x8*)(pwt + ((wcg2 * 3 + j) * 6 + kc) * 512 + lane * 8);
      #pragma unroll
      for (int i = 0; i < 2; i++)
        #pragma unroll
        for (int j = 0; j < 3; j++)
          accp[i][j] = __builtin_amdgcn_mfma_f32_16x16x32_bf16(af[i], bfr[j], accp[i][j], 0, 0, 0);
    }
    #pragma unroll
    for (int i = 0; i < 2; i++) {
      #pragma unroll
      for (int j = 0; j < 3; j++) {
        #pragma unroll
        for (int r = 0; r < 4; r++) {
          const long m = m0 + wrr2 + i * 16 + lg * 4 + r;
          const int cn = wcg2 * 48 + j * 16 + lr;
          const float v = accp[i][j][r] + pb[cn];
          const long b_ = m >> 6; const int n = (int)(m & 63);
          const int b = (int)(b_ >> 10), wk = (int)(b_ & 1023), wi = wk >> 5, wj = wk & 31;
          const int i_ = n >> 3, j_ = n & 7;
          const int hf = (wi * 8 + i_ + 4) & 255, wf = (wj * 8 + j_ + 4) & 255;
          const long g = (((long)b * 256 + hf) * 256 + wf) * 192 + cn;
          hbuf[g] = x[g] + v;   // h = shortcut + proj(attn)
        }
      }
    }
  }
}

// ------------ fused MLP v6 (R21-proven, ~340us): out = h + fc2(gelu(fc1(LN2(h)))) ------------
__global__ __launch_bounds__(512, 2) void mlp_fused(const float* __restrict__ hbuf,
                                                    const float* __restrict__ n2w,
                                                    const float* __restrict__ n2b,
                                                    const bf16* __restrict__ w1t,
                                                    const float* __restrict__ b1,
                                                    const bf16* __restrict__ w2t,
                                                    const float* __restrict__ b2,
                                                    float* __restrict__ outp) {
  __shared__ __align__(16) char smem[122880];
  char* Ab = smem;          // h_ln tile: 3 groups x [64 rows][8 slots][16B] = 24576
  char* G  = smem + 24576;  // g tile: [64 rows][96 slots][16B] = 98304

  const int tid = threadIdx.x;
  const long m0 = (long)blockIdx.x * 64;
  const int lane = tid & 63, wid = tid >> 6;
  const int lg = lane >> 4, lr = lane & 15;

  #pragma unroll
  for (int t8 = 0; t8 < 8; t8++) {
    const int row = wid * 8 + t8;
    const long g = (m0 + row) * 192;
    const float x0 = hbuf[g + lane], x1 = hbuf[g + 64 + lane], x2 = hbuf[g + 128 + lane];
    float s = x0 + x1 + x2;
    float s2 = x0 * x0 + x1 * x1 + x2 * x2;
    #pragma unroll
    for (int msk = 1; msk < 64; msk <<= 1) { s += __shfl_xor(s, msk); s2 += __shfl_xor(s2, msk); }
    const float mu = s * (1.0f / 192.0f);
    const float rstd = rsqrtf(s2 * (1.0f / 192.0f) - mu * mu + 1e-5f);
    #pragma unroll
    for (int p = 0; p < 3; p++) {
      const int ch = p * 64 + lane;
      const float xv = (p == 0) ? x0 : (p == 1) ? x1 : x2;
      const float v = (xv - mu) * rstd * n2w[ch] + n2b[ch];
      const int c = (ch >> 3) & 7;
      const int slot = c ^ (row & 7);
      *(unsigned short*)(Ab + p * 8192 + row * 128 + slot * 16 + (ch & 7) * 2) =
          __builtin_bit_cast(unsigned short, __float2bfloat16(v));
    }
  }
  __syncthreads();

  f32x4 acc1[4][6];
  #pragma unroll
  for (int i = 0; i < 4; i++)
    #pragma unroll
    for (int j = 0; j < 6; j++) acc1[i][j] = (f32x4){0.f, 0.f, 0.f, 0.f};

  const int c16base = wid * 6;
  #pragma unroll
  for (int kc = 0; kc < 6; kc++) {
    const int q = kc >> 1;
    const int kk = (kc & 1) * 4 + lg;
    bf16x8 af[4], bfr[6];
    #pragma unroll
    for (int i = 0; i < 4; i++) {
      const int row = i * 16 + lr;
      af[i] = *(const bf16x8*)(Ab + q * 8192 + row * 128 + ((kk ^ (row & 7)) * 16));
    }
    #pragma unroll
    for (int j = 0; j < 6; j++)
      bfr[j] = *(const bf16x8*)(w1t + ((c16base + j) * 6 + kc) * 512 + lane * 8);
    #pragma unroll
    for (int i = 0; i < 4; i++)
      #pragma unroll
      for (int j = 0; j < 6; j++)
        acc1[i][j] = __builtin_amdgcn_mfma_f32_16x16x32_bf16(af[i], bfr[j], acc1[i][j], 0, 0, 0);
  }

  #pragma unroll
  for (int j = 0; j < 6; j++) {
    const int n = wid * 96 + j * 16 + lr;
    const float bj = b1[n];
    const int c = n >> 3;
    #pragma unroll
    for (int i = 0; i < 4; i++) {
      #pragma unroll
      for (int r = 0; r < 4; r++) {
        const int m = i * 16 + lg * 4 + r;
        const int slot = (c & ~7) | ((c & 7) ^ (m & 7));
        *(unsigned short*)(G + m * 1536 + slot * 16 + (n & 7) * 2) =
            __builtin_bit_cast(unsigned short, __float2bfloat16(gelu_f(acc1[i][j][r] + bj)));
      }
    }
  }
  __syncthreads();

  const int wt = wid >> 2, wn = wid & 3;
  f32x4 acc2[2][3];
  #pragma unroll
  for (int i = 0; i < 2; i++)
    #pragma unroll
    for (int j = 0; j < 3; j++) acc2[i][j] = (f32x4){0.f, 0.f, 0.f, 0.f};

  for (int kt = 0; kt < 24; kt++) {
    const int c2 = kt * 4 + lg;
    bf16x8 af2[2], bfr2[3];
    #pragma unroll
    for (int i = 0; i < 2; i++) {
      const int grow = wt * 32 + i * 16 + lr;
      const int slot2 = (c2 & ~7) | ((c2 & 7) ^ (grow & 7));
      af2[i] = *(const bf16x8*)(G + grow * 1536 + slot2 * 16);
    }
    #pragma unroll
    for (int j = 0; j < 3; j++)
      bfr2[j] = *(const bf16x8*)(w2t + ((wn * 3 + j) * 24 + kt) * 512 + lane * 8);
    #pragma unroll
    for (int i = 0; i < 2; i++)
      #pragma unroll
      for (int j = 0; j < 3; j++)
        acc2[i][j] = __builtin_amdgcn_mfma_f32_16x16x32_bf16(af2[i], bfr2[j], acc2[i][j], 0, 0, 0);
  }

  #pragma unroll
  for (int j = 0; j < 3; j++) {
    const int cn = wn * 48 + j * 16 + lr;
    const float bj = b2[cn];
    #pragma unroll
    for (int i = 0; i < 2; i++) {
      #pragma unroll
      for (int r = 0; r < 4; r++) {
        const long m = m0 + wt * 32 + i * 16 + lg * 4 + r;
        outp[m * 192 + cn] = acc2[i][j][r] + bj + hbuf[m * 192 + cn];
      }
    }
  }
}

extern "C" void kernel_launch(void* const* d_in, const int* in_sizes, int n_in,
                              void* d_out, int out_size, void* d_ws, size_t ws_size,
                              hipStream_t stream) {
  const float* x      = (const float*)d_in[0];
  const float* qkv_w  = (const float*)d_in[1];
  const float* qkv_b  = (const float*)d_in[2];
  const float* proj_w = (const float*)d_in[3];
  const float* proj_b = (const float*)d_in[4];
  const float* rpb    = (const float*)d_in[5];
  const float* n1_w   = (const float*)d_in[6];
  const float* n1_b   = (const float*)d_in[7];
  const float* n2_w   = (const float*)d_in[8];
  const float* n2_b   = (const float*)d_in[9];
  const float* fc1_w  = (const float*)d_in[10];
  const float* fc1_b  = (const float*)d_in[11];
  const float* fc2_w  = (const float*)d_in[12];
  const float* fc2_b  = (const float*)d_in[13];

  char* ws = (char*)d_ws;
  // workspace: all weights fragment-order [0, 884736); hbuf at 1 MiB (+201.3 MB).
  bf16* qkvw_t  = (bf16*)(ws);
  bf16* projw_t = (bf16*)(ws + 221184);
  bf16* fc1w_t  = (bf16*)(ws + 294912);
  bf16* fc2w_t  = (bf16*)(ws + 589824);
  float* hbuf   = (float*)(ws + (1L << 20));

  cvt_frag_kernel<192, 6><<<432, 256, 0, stream>>>(qkv_w, qkvw_t, 110592);
  cvt_frag_kernel<192, 6><<<144, 256, 0, stream>>>(proj_w, projw_t, 36864);
  cvt_frag_kernel<192, 6><<<576, 256, 0, stream>>>(fc1_w, fc1w_t, 147456);
  cvt_frag_kernel<768, 24><<<576, 256, 0, stream>>>(fc2_w, fc2w_t, 147456);

  // fused LN1 + QKV + attention + proj + residual -> hbuf (one block per window)
  win_attn<<<4096, 512, 0, stream>>>(x, n1_w, n1_b, qkvw_t, qkv_b, rpb, projw_t, proj_b, hbuf);
  // fused LN2 + MLP: out = h + fc2(gelu(fc1(LN2(h))))
  mlp_fused<<<4096, 512, 0, stream>>>(hbuf, n2_w, n2_b, fc1w_t, fc1_b, fc2w_t, fc2_b,
                                      (float*)d_out);
}